// Round 4
// baseline (70.434 us; speedup 1.0000x reference)
//
#include <hip/hip_runtime.h>
#include <math.h>

// ChamferLossWholeImage: N=2000 render points vs 256x256 pixel grid.
// out = sum_n min_m d(n,m) + sum_m min_n d(n,m), d = L2 distance.
//
// Point side: nearest pixel on a regular integer grid is closed-form.
// Pixel side: brute force on d^2 (sqrt deferred to the reduce), split over
// NCHUNK point-chunks for occupancy. Each (pixel-tile, chunk) block writes
// partial mins to its OWN ws slot with plain coalesced stores (no atomics,
// no ws init). Points are read with wave-uniform addresses -> compiler
// scalarizes to s_load (constant cache); no LDS, no __syncthreads.
//
// NOTE (measured R2/R3 rocprof): the harness re-poisons the 256 MiB d_ws at
// ~41 us per timed iteration (fillBufferAligned @ ~84% HBM peak) plus ~14 us
// of restore/graph overhead -- a ~55 us floor outside this file's control.
// Controllable kernel time is ~15 us in R3; this round targets ~8 us.

#define GRID_W 256
#define NCHUNK 32

__global__ __launch_bounds__(256) void chamfer_pixel_partial(
    const float2* __restrict__ pts, int N, int chunkLen, int M,
    float* __restrict__ wspart, float* __restrict__ out) {
    // zero the scalar output once; reduce kernel (next in stream) atomicAdds
    if (blockIdx.x == 0 && blockIdx.y == 0 && threadIdx.x == 0) out[0] = 0.0f;

    const int base = blockIdx.y * chunkLen;
    const int cnt  = min(chunkLen, max(N - base, 0));

    const int t = threadIdx.x;
    const int ci0 = 2 * (t & 127);
    const float c0 = (float)ci0;
    const float c1 = c0 + 1.0f;
    const int rbase = blockIdx.x * 8 + (t >> 7) * 4;
    const float r0 = (float)rbase;
    const float r1 = (float)(rbase + 1);
    const float r2 = (float)(rbase + 2);
    const float r3 = (float)(rbase + 3);

    const float INF = 3.4e38f;
    float m00 = INF, m01 = INF, m10 = INF, m11 = INF;
    float m20 = INF, m21 = INF, m30 = INF, m31 = INF;

#pragma unroll 4
    for (int j = 0; j < cnt; ++j) {
        const float2 p = pts[base + j];  // wave-uniform -> s_load, K$-resident
        const float dx0 = p.x - c0, dx1 = p.x - c1;
        const float dxs0 = dx0 * dx0, dxs1 = dx1 * dx1;
        float dy;
        dy = p.y - r0;
        m00 = fminf(m00, fmaf(dy, dy, dxs0));
        m01 = fminf(m01, fmaf(dy, dy, dxs1));
        dy = p.y - r1;
        m10 = fminf(m10, fmaf(dy, dy, dxs0));
        m11 = fminf(m11, fmaf(dy, dy, dxs1));
        dy = p.y - r2;
        m20 = fminf(m20, fmaf(dy, dy, dxs0));
        m21 = fminf(m21, fmaf(dy, dy, dxs1));
        dy = p.y - r3;
        m30 = fminf(m30, fmaf(dy, dy, dxs0));
        m31 = fminf(m31, fmaf(dy, dy, dxs1));
    }

    // ALWAYS store (even if cnt==0, store INF): an unwritten slot keeps the
    // harness poison 0xAAAAAAAA, which decodes to a NEGATIVE float and would
    // corrupt the min / NaN the sqrt in the reduce.
    float2* w = (float2*)(wspart + (size_t)blockIdx.y * M) +
                (size_t)rbase * (GRID_W / 2) + (ci0 >> 1);
    const int rs = GRID_W / 2;
    w[0 * rs] = make_float2(m00, m01);
    w[1 * rs] = make_float2(m10, m11);
    w[2 * rs] = make_float2(m20, m21);
    w[3 * rs] = make_float2(m30, m31);
}

__global__ __launch_bounds__(256) void chamfer_reduce(
    const float* __restrict__ wspart, const float2* __restrict__ pts,
    int N, int M, int H, int W, float* __restrict__ out) {
    __shared__ float red[4];
    const int gid = blockIdx.x * 256 + threadIdx.x;  // handles pixels 4g..4g+3

    float4 m = ((const float4*)wspart)[gid];
#pragma unroll 8
    for (int c = 1; c < NCHUNK; ++c) {
        const float4 v = ((const float4*)(wspart + (size_t)c * M))[gid];
        m.x = fminf(m.x, v.x);
        m.y = fminf(m.y, v.y);
        m.z = fminf(m.z, v.z);
        m.w = fminf(m.w, v.w);
    }
    float s = sqrtf(m.x) + sqrtf(m.y) + sqrtf(m.z) + sqrtf(m.w);

    if (blockIdx.x == 0) {  // point side: nearest pixel = clamp(rint(p))
        for (int i = threadIdx.x; i < N; i += 256) {
            const float2 p = pts[i];
            const float nx = fminf(fmaxf(rintf(p.x), 0.0f), (float)(W - 1));
            const float ny = fminf(fmaxf(rintf(p.y), 0.0f), (float)(H - 1));
            const float dx = p.x - nx, dy = p.y - ny;
            s += sqrtf(fmaf(dx, dx, dy * dy));
        }
    }

    for (int off = 32; off > 0; off >>= 1)
        s += __shfl_down(s, off, 64);
    const int lane = threadIdx.x & 63;
    const int wid  = threadIdx.x >> 6;
    if (lane == 0) red[wid] = s;
    __syncthreads();
    if (threadIdx.x == 0)
        atomicAdd(out, red[0] + red[1] + red[2] + red[3]);
}

extern "C" void kernel_launch(void* const* d_in, const int* in_sizes, int n_in,
                              void* d_out, int out_size, void* d_ws, size_t ws_size,
                              hipStream_t stream) {
    const float2* pts = (const float2*)d_in[0];
    const int N = in_sizes[0] / 2;       // (N,2) points
    const int W = GRID_W;
    const int H = in_sizes[1] / W;       // img_ref is (H,W)
    const int M = H * W;
    float* out = (float*)d_out;
    float* wspart = (float*)d_ws;        // NCHUNK * M floats = 8 MB

    const int chunkLen = (N + NCHUNK - 1) / NCHUNK;
    dim3 grid(H / 8, NCHUNK);            // 32 x 32 = 1024 blocks
    chamfer_pixel_partial<<<grid, 256, 0, stream>>>(pts, N, chunkLen, M, wspart, out);

    chamfer_reduce<<<M / 1024, 256, 0, stream>>>(wspart, pts, N, M, H, W, out);
}